// Round 1
// baseline (94.875 us; speedup 1.0000x reference)
//
#include <hip/hip_runtime.h>
#include <math.h>

#define HEADS 8
#define BATCH 4
#define SEQ 2048
#define CDIM 32
#define WINDOW 10
#define WSZ (2 * WINDOW + 1)   // 21 keys per query row

// One 32-lane group per query row; lane = channel index (CDIM == 32).
// row = h*(BATCH*SEQ) + n*SEQ + s  ==> Q/K/V/G flat base = row*CDIM.
__global__ __launch_bounds__(256) void lwin_attn_kernel(
    const float* __restrict__ Q, const float* __restrict__ K,
    const float* __restrict__ V, const float* __restrict__ G,
    const unsigned char* __restrict__ seqMask, float* __restrict__ out)
{
    const int group = threadIdx.x >> 5;            // 0..7: row-group within block
    const int lane  = threadIdx.x & 31;            // channel
    const int row   = blockIdx.x * 8 + group;      // 0..HEADS*BATCH*SEQ-1

    const int h   = row >> 13;                     // / (BATCH*SEQ) = /8192
    const int rem = row & 8191;
    const int n   = rem >> 11;                     // / SEQ
    const int s   = rem & 2047;                    // % SEQ

    const float scale = 0.17677669529663687f;      // 1/sqrt(32)
    const float q = Q[row * CDIM + lane] * scale;
    const float g = G[row * CDIM + lane];
    const int base_hn = (row - s) * CDIM;          // (h*BATCH+n)*SEQ*CDIM

    // ---- QK^T over the band (branch-free: clamp address, mask score) ----
    float score[WSZ];
#pragma unroll
    for (int j = 0; j < WSZ; ++j) {
        const int t  = s - WINDOW + j;
        const int tc = min(max(t, 0), SEQ - 1);
        float part = q * K[base_hn + tc * CDIM + lane];
        part += __shfl_xor(part, 16, 32);
        part += __shfl_xor(part, 8, 32);
        part += __shfl_xor(part, 4, 32);
        part += __shfl_xor(part, 2, 32);
        part += __shfl_xor(part, 1, 32);
        const bool valid = (t >= 0) && (t < SEQ) && (seqMask[n * SEQ + tc] == 0);
        score[j] = valid ? part : -INFINITY;
    }

    // ---- softmax over 21 scores (all lanes hold full row copies) ----
    float m = -INFINITY;
#pragma unroll
    for (int j = 0; j < WSZ; ++j) m = fmaxf(m, score[j]);
    float sum = 0.f;
    float p[WSZ];
#pragma unroll
    for (int j = 0; j < WSZ; ++j) {
        const float e = (score[j] == -INFINITY) ? 0.f : __expf(score[j] - m);
        p[j] = e;
        sum += e;
    }
    const float inv = 1.0f / sum;

    // ---- PV + gate ----
    float acc = 0.f;
#pragma unroll
    for (int j = 0; j < WSZ; ++j) {
        const int t  = s - WINDOW + j;
        const int tc = min(max(t, 0), SEQ - 1);
        acc = fmaf(p[j], V[base_hn + tc * CDIM + lane], acc);
    }

    // out[n, s, h, i]
    out[((n * SEQ + s) * HEADS + h) * CDIM + lane] = acc * inv * g;
}

extern "C" void kernel_launch(void* const* d_in, const int* in_sizes, int n_in,
                              void* d_out, int out_size, void* d_ws, size_t ws_size,
                              hipStream_t stream) {
    const float* Q = (const float*)d_in[0];
    const float* K = (const float*)d_in[1];
    const float* V = (const float*)d_in[2];
    const float* G = (const float*)d_in[3];
    const unsigned char* seqMask = (const unsigned char*)d_in[4];
    float* out = (float*)d_out;

    const int rows = HEADS * BATCH * SEQ;          // 65536
    const int blocks = rows / 8;                   // 8192 blocks of 256 threads
    lwin_attn_kernel<<<blocks, 256, 0, stream>>>(Q, K, V, G, seqMask, out);
}

// Round 2
// 37.584 us; speedup vs baseline: 2.5243x; 2.5243x over previous
//
#include <hip/hip_runtime.h>
#include <math.h>

#define HEADS 8
#define BATCH 4
#define SEQ 2048
#define CDIM 32
#define WINDOW 10
#define WSZ (2 * WINDOW + 1)   // 21 keys per query row

// 8 lanes per query row; each lane owns 4 channels (float4). CDIM = 32 = 8*4.
// Per key: one coalesced float4 load per lane (8 lanes cover the 128B K row),
// 4 FMAs, 3-stage xor-shuffle reduce within the 8-lane group.
__global__ __launch_bounds__(256) void lwin_attn_kernel(
    const float* __restrict__ Q, const float* __restrict__ K,
    const float* __restrict__ V, const float* __restrict__ G,
    const unsigned char* __restrict__ seqMask, float* __restrict__ out)
{
    const int tid = blockIdx.x * 256 + threadIdx.x;
    const int sub = tid & 7;                 // channel-quad index 0..7
    const int row = tid >> 3;                // query row 0..HEADS*BATCH*SEQ-1

    const int h   = row >> 13;               // / (BATCH*SEQ)
    const int rem = row & 8191;
    const int n   = rem >> 11;               // / SEQ
    const int s   = rem & 2047;              // % SEQ

    const int base_hn = (row - s) * CDIM;    // (h*BATCH+n)*SEQ*CDIM
    const int c0 = sub * 4;

    const float scale = 0.17677669529663687f;   // 1/sqrt(32)
    float4 q = *(const float4*)&Q[row * CDIM + c0];
    q.x *= scale; q.y *= scale; q.z *= scale; q.w *= scale;

    // ---- QK^T over the band (branch-free: clamp address, mask score) ----
    float score[WSZ];
#pragma unroll
    for (int j = 0; j < WSZ; ++j) {
        const int t  = s - WINDOW + j;
        const int tc = min(max(t, 0), SEQ - 1);
        const float4 k = *(const float4*)&K[base_hn + tc * CDIM + c0];
        float part = q.x * k.x + q.y * k.y + q.z * k.z + q.w * k.w;
        part += __shfl_xor(part, 1);
        part += __shfl_xor(part, 2);
        part += __shfl_xor(part, 4);
        const bool valid = (t >= 0) && (t < SEQ) && (seqMask[n * SEQ + tc] == 0);
        score[j] = valid ? part : -1e30f;    // finite sentinel: exp underflows to 0
    }

    // ---- softmax over 21 scores (replicated across the 8 lanes) ----
    float m = -1e30f;
#pragma unroll
    for (int j = 0; j < WSZ; ++j) m = fmaxf(m, score[j]);
    float sum = 0.f;
#pragma unroll
    for (int j = 0; j < WSZ; ++j) {
        const float e = __expf(score[j] - m);
        score[j] = e;
        sum += e;
    }
    const float inv = 1.0f / sum;

    // ---- PV + gate ----
    float4 acc = make_float4(0.f, 0.f, 0.f, 0.f);
#pragma unroll
    for (int j = 0; j < WSZ; ++j) {
        const int t  = s - WINDOW + j;
        const int tc = min(max(t, 0), SEQ - 1);
        const float4 v = *(const float4*)&V[base_hn + tc * CDIM + c0];
        acc.x = fmaf(score[j], v.x, acc.x);
        acc.y = fmaf(score[j], v.y, acc.y);
        acc.z = fmaf(score[j], v.z, acc.z);
        acc.w = fmaf(score[j], v.w, acc.w);
    }

    const float4 g = *(const float4*)&G[row * CDIM + c0];
    float4 o;
    o.x = acc.x * inv * g.x;
    o.y = acc.y * inv * g.y;
    o.z = acc.z * inv * g.z;
    o.w = acc.w * inv * g.w;

    // out[n, s, h, i]
    *(float4*)&out[((n * SEQ + s) * HEADS + h) * CDIM + c0] = o;
}

extern "C" void kernel_launch(void* const* d_in, const int* in_sizes, int n_in,
                              void* d_out, int out_size, void* d_ws, size_t ws_size,
                              hipStream_t stream) {
    const float* Q = (const float*)d_in[0];
    const float* K = (const float*)d_in[1];
    const float* V = (const float*)d_in[2];
    const float* G = (const float*)d_in[3];
    const unsigned char* seqMask = (const unsigned char*)d_in[4];
    float* out = (float*)d_out;

    const int total_threads = HEADS * BATCH * SEQ * 8;   // 8 lanes per query row
    const int blocks = total_threads / 256;              // 2048 blocks
    lwin_attn_kernel<<<blocks, 256, 0, stream>>>(Q, K, V, G, seqMask, out);
}

// Round 3
// 17.161 us; speedup vs baseline: 5.5285x; 2.1901x over previous
//
#include <hip/hip_runtime.h>
#include <math.h>

#define HEADS 8
#define BATCH 4
#define SEQ 2048
#define CDIM 32
#define WINDOW 10
#define WSZ 21                       // 2*WINDOW+1 keys per row
#define RPB 32                       // query rows per block
#define BAND (RPB + 2 * WINDOW)      // 52 band rows staged in LDS

// DPP cross-lane add helpers (pure VALU, no DS pipe).
// xor1: quad_perm [1,0,3,2] = 0xB1 ; xor2: quad_perm [2,3,0,1] = 0x4E ;
// final stage: row_half_mirror (0x141) — valid because after xor1+xor2 all
// 4 lanes of a quad hold the same partial, so any cross-quad lane works.
#define DPP_ADD(x, ctrl) \
    ((x) + __int_as_float(__builtin_amdgcn_mov_dpp(__float_as_int(x), (ctrl), 0xF, 0xF, true)))

__global__ __launch_bounds__(256) void lwin_attn_kernel(
    const float* __restrict__ Q, const float* __restrict__ K,
    const float* __restrict__ V, const float* __restrict__ G,
    const unsigned char* __restrict__ seqMask, float* __restrict__ out)
{
    __shared__ float k_lds[BAND][CDIM];   // 6656 B
    __shared__ float v_lds[BAND][CDIM];   // 6656 B
    __shared__ unsigned int bm_lds[2];    // band invalid-mask (bit i = band row i invalid)

    const int b  = blockIdx.x;
    const int hn = b >> 6;                       // (h*BATCH + n), 64 blocks per (h,n)
    const int s0 = (b & 63) * RPB;
    const int n  = hn & 3;
    const int h  = hn >> 2;
    const int base_hn = hn * SEQ * CDIM;

    // ---- band invalid mask: one ballot by wave 0 ----
    if (threadIdx.x < 64) {
        const int i  = threadIdx.x;
        const int t  = s0 - WINDOW + i;
        const int tc = min(max(t, 0), SEQ - 1);
        const bool invalid =
            (i < BAND) && ((t < 0) || (t >= SEQ) || (seqMask[n * SEQ + tc] != 0));
        const unsigned long long bm = __ballot(invalid);
        if (threadIdx.x == 0) {
            bm_lds[0] = (unsigned int)bm;
            bm_lds[1] = (unsigned int)(bm >> 32);
        }
    }

    // ---- stage K and V band rows into LDS (coalesced float4) ----
#pragma unroll
    for (int it = 0; it < 4; ++it) {
        const int task = threadIdx.x + it * 256;          // 0..1023, need 832
        if (task < 2 * BAND * 8) {
            const bool isK = task < BAND * 8;
            const int  tt  = isK ? task : task - BAND * 8;
            const int  i   = tt >> 3;
            const int  ch  = (tt & 7) * 4;
            const int  t   = s0 - WINDOW + i;
            const int  tc  = min(max(t, 0), SEQ - 1);
            const float* src = isK ? K : V;
            float*       dst = isK ? &k_lds[0][0] : &v_lds[0][0];
            const float4 val = *(const float4*)&src[base_hn + tc * CDIM + ch];
            *(float4*)&dst[i * CDIM + ch] = val;
        }
    }
    __syncthreads();

    // ---- per-row compute: 8 lanes per row, 4 channels per lane ----
    const int r_loc = threadIdx.x >> 3;          // 0..31
    const int sub   = threadIdx.x & 7;
    const int c0    = sub * 4;
    const int s     = s0 + r_loc;
    const int row   = hn * SEQ + s;

    const float scale = 0.17677669529663687f;    // 1/sqrt(32)
    float4 q = *(const float4*)&Q[row * CDIM + c0];
    q.x *= scale; q.y *= scale; q.z *= scale; q.w *= scale;

    const unsigned long long bm =
        ((unsigned long long)bm_lds[1] << 32) | (unsigned long long)bm_lds[0];
    const unsigned int mybm = (unsigned int)(bm >> r_loc);   // bit j: key j invalid

    float score[WSZ];
#pragma unroll
    for (int j = 0; j < WSZ; ++j) {
        const float4 k = *(const float4*)&k_lds[r_loc + j][c0];
        float part = q.x * k.x + q.y * k.y + q.z * k.z + q.w * k.w;
        part = DPP_ADD(part, 0xB1);    // xor1 (quad_perm)
        part = DPP_ADD(part, 0x4E);    // xor2 (quad_perm)
        part = DPP_ADD(part, 0x141);   // cross-quad (row_half_mirror)
        score[j] = ((mybm >> j) & 1u) ? -1e30f : part;
    }

    // ---- softmax over 21 scores (replicated across the 8 lanes) ----
    float m = -1e30f;
#pragma unroll
    for (int j = 0; j < WSZ; ++j) m = fmaxf(m, score[j]);
    float sum = 0.f;
#pragma unroll
    for (int j = 0; j < WSZ; ++j) {
        const float e = __expf(score[j] - m);
        score[j] = e;
        sum += e;
    }
    const float inv = 1.0f / sum;

    // ---- PV from LDS + gate ----
    float4 acc = make_float4(0.f, 0.f, 0.f, 0.f);
#pragma unroll
    for (int j = 0; j < WSZ; ++j) {
        const float4 v = *(const float4*)&v_lds[r_loc + j][c0];
        acc.x = fmaf(score[j], v.x, acc.x);
        acc.y = fmaf(score[j], v.y, acc.y);
        acc.z = fmaf(score[j], v.z, acc.z);
        acc.w = fmaf(score[j], v.w, acc.w);
    }

    const float4 g = *(const float4*)&G[row * CDIM + c0];
    float4 o;
    o.x = acc.x * inv * g.x;
    o.y = acc.y * inv * g.y;
    o.z = acc.z * inv * g.z;
    o.w = acc.w * inv * g.w;

    // out[n, s, h, i]
    *(float4*)&out[((n * SEQ + s) * HEADS + h) * CDIM + c0] = o;
}

extern "C" void kernel_launch(void* const* d_in, const int* in_sizes, int n_in,
                              void* d_out, int out_size, void* d_ws, size_t ws_size,
                              hipStream_t stream) {
    const float* Q = (const float*)d_in[0];
    const float* K = (const float*)d_in[1];
    const float* V = (const float*)d_in[2];
    const float* G = (const float*)d_in[3];
    const unsigned char* seqMask = (const unsigned char*)d_in[4];
    float* out = (float*)d_out;

    const int blocks = HEADS * BATCH * (SEQ / RPB);   // 8*4*64 = 2048
    lwin_attn_kernel<<<blocks, 256, 0, stream>>>(Q, K, V, G, seqMask, out);
}